// Round 1
// baseline (767.874 us; speedup 1.0000x reference)
//
#include <hip/hip_runtime.h>

#define IN_F 128
#define OUT_F 64
#define NEG_SLOPE 0.2f

// ---- monotone float<->uint encoding for atomicMax on floats ----
__device__ __forceinline__ unsigned f2key(float f) {
    unsigned b = __float_as_uint(f);
    return (b & 0x80000000u) ? ~b : (b | 0x80000000u);
}
__device__ __forceinline__ float key2f(unsigned k) {
    unsigned b = (k & 0x80000000u) ? (k & 0x7FFFFFFFu) : ~k;
    return __uint_as_float(b);
}

// Pass 1: Wh = x @ W  [N,64]; e_left = Wh@a_l; e_right = Wh@a_r.
// One row per wave; lane = output column. W staged in LDS (32 KB).
__global__ void __launch_bounds__(256) gemm_eproj(
    const float* __restrict__ x, const float* __restrict__ W,
    const float* __restrict__ a_l, const float* __restrict__ a_r,
    float* __restrict__ Wh, float* __restrict__ el, float* __restrict__ er,
    int N)
{
    __shared__ float Ws[IN_F][OUT_F];   // 32 KB
    for (int i = threadIdx.x; i < IN_F * OUT_F; i += blockDim.x)
        (&Ws[0][0])[i] = W[i];
    __syncthreads();

    const int lane = threadIdx.x & 63;
    const int wid  = threadIdx.x >> 6;
    const int wpb  = blockDim.x >> 6;
    const float al = a_l[lane];
    const float ar = a_r[lane];

    for (int row = blockIdx.x * wpb + wid; row < N; row += gridDim.x * wpb) {
        const float* xr = x + (size_t)row * IN_F;
        float acc = 0.f;
#pragma unroll
        for (int k = 0; k < IN_F; ++k)
            acc = fmaf(xr[k], Ws[k][lane], acc);   // xr[k] uniform -> broadcast; Ws 2-way bank (free)
        Wh[(size_t)row * OUT_F + lane] = acc;

        float sl = acc * al, sr = acc * ar;
#pragma unroll
        for (int off = 32; off; off >>= 1) {
            sl += __shfl_down(sl, off);
            sr += __shfl_down(sr, off);
        }
        if (lane == 0) { el[row] = sl; er[row] = sr; }
    }
}

// Pass 2: per-edge logit + leaky relu; segment max via atomicMax on key
__global__ void __launch_bounds__(256) edge_logits(
    const int* __restrict__ src, const int* __restrict__ dst,
    const float* __restrict__ el, const float* __restrict__ er,
    float* __restrict__ ebuf, unsigned* __restrict__ emax, int E)
{
    for (int e = blockIdx.x * blockDim.x + threadIdx.x; e < E;
         e += gridDim.x * blockDim.x) {
        int s = src[e], d = dst[e];
        float v = el[s] + er[d];
        v = v > 0.f ? v : NEG_SLOPE * v;
        ebuf[e] = v;
        atomicMax(&emax[s], f2key(v));
    }
}

// Pass 3: exp(e - max) + segment sum
__global__ void __launch_bounds__(256) edge_exp(
    const int* __restrict__ src, float* __restrict__ ebuf,
    const unsigned* __restrict__ emax, float* __restrict__ esum, int E)
{
    for (int e = blockIdx.x * blockDim.x + threadIdx.x; e < E;
         e += gridDim.x * blockDim.x) {
        int s = src[e];
        float ex = expf(ebuf[e] - key2f(emax[s]));
        ebuf[e] = ex;
        atomicAdd(&esum[s], ex);
    }
}

// Pass 4: out[src] += alpha * Wh[dst]   — one wave per edge, lane = column
__global__ void __launch_bounds__(256) scatter_msg(
    const int* __restrict__ src, const int* __restrict__ dst,
    const float* __restrict__ ebuf, const float* __restrict__ esum,
    const float* __restrict__ Wh, float* __restrict__ out, int E)
{
    const int lane = threadIdx.x & 63;
    const int gw   = (blockIdx.x * blockDim.x + threadIdx.x) >> 6;
    const int nw   = (gridDim.x * blockDim.x) >> 6;
    for (int e = gw; e < E; e += nw) {
        int s = src[e], d = dst[e];
        float alpha = ebuf[e] / (esum[s] + 1e-9f);
        float v = alpha * Wh[(size_t)d * OUT_F + lane];
        atomicAdd(&out[(size_t)s * OUT_F + lane], v);
    }
}

// Pass 5: relu in place (float4)
__global__ void __launch_bounds__(256) relu_k(float* __restrict__ out, int n4)
{
    int i = blockIdx.x * blockDim.x + threadIdx.x;
    if (i < n4) {
        float4 v = reinterpret_cast<float4*>(out)[i];
        v.x = fmaxf(v.x, 0.f); v.y = fmaxf(v.y, 0.f);
        v.z = fmaxf(v.z, 0.f); v.w = fmaxf(v.w, 0.f);
        reinterpret_cast<float4*>(out)[i] = v;
    }
}

extern "C" void kernel_launch(void* const* d_in, const int* in_sizes, int n_in,
                              void* d_out, int out_size, void* d_ws, size_t ws_size,
                              hipStream_t stream)
{
    const float* x   = (const float*)d_in[0];
    const float* W   = (const float*)d_in[1];
    const float* a_l = (const float*)d_in[2];
    const float* a_r = (const float*)d_in[3];
    const int*   ei  = (const int*)d_in[4];   // edge_index flattened [2,E]

    const int N = in_sizes[0] / IN_F;
    const int E = in_sizes[4] / 2;
    const int* src = ei;
    const int* dst = ei + E;

    float* out = (float*)d_out;

    // workspace carve-up
    char* ws = (char*)d_ws;
    float*    Wh   = (float*)(ws);                                   // N*64*4
    float*    el   = (float*)(ws + (size_t)N * OUT_F * 4);           // N*4
    float*    er   = (float*)(ws + (size_t)N * OUT_F * 4 + (size_t)N * 4);
    unsigned* emax = (unsigned*)(ws + (size_t)N * OUT_F * 4 + (size_t)N * 8);
    float*    esum = (float*)(ws + (size_t)N * OUT_F * 4 + (size_t)N * 12);
    float*    ebuf = (float*)(ws + (size_t)N * OUT_F * 4 + (size_t)N * 16);  // E*4

    // zero-init accumulators (ws/out are poisoned 0xAA before every call)
    hipMemsetAsync(emax, 0, (size_t)N * 4, stream);                  // key 0 < key(-inf)
    hipMemsetAsync(esum, 0, (size_t)N * 4, stream);
    hipMemsetAsync(out,  0, (size_t)N * OUT_F * 4, stream);

    // pass 1
    gemm_eproj<<<1024, 256, 0, stream>>>(x, W, a_l, a_r, Wh, el, er, N);

    // pass 2
    int blk = 256;
    int grid_e = (E + blk - 1) / blk;  if (grid_e > 2048) grid_e = 2048;
    edge_logits<<<grid_e, blk, 0, stream>>>(src, dst, el, er, ebuf, emax, E);

    // pass 3
    edge_exp<<<grid_e, blk, 0, stream>>>(src, ebuf, emax, esum, E);

    // pass 4: one wave per edge
    scatter_msg<<<2048, 256, 0, stream>>>(src, dst, ebuf, esum, Wh, out, E);

    // pass 5
    int n4 = N * OUT_F / 4;
    relu_k<<<(n4 + 255) / 256, 256, 0, stream>>>(out, n4);
}